// Round 17
// baseline (233.752 us; speedup 1.0000x reference)
//
#include <hip/hip_runtime.h>
#include <hip/hip_bf16.h>
#include <math.h>

#define N_NODES 30000
#define NHEAD   4
#define HDIM    64
#define NTYPES  5
#define EPT     40000
#define TE      (NTYPES * EPT)
#define KDIM    256
#define NCAT    1792   // 1280 Ktil | 256 Q | 256 V
#define NBLK    118    // ceil(30000/256)

typedef __attribute__((ext_vector_type(8))) short short8;
typedef __attribute__((ext_vector_type(4))) float f32x4;

__device__ __forceinline__ unsigned short f2bf(float f) {
    __hip_bfloat16 h = __float2bfloat16(f);
    return *reinterpret_cast<unsigned short*>(&h);
}
__device__ __forceinline__ float bf2f(unsigned short u) {
    return __uint_as_float((unsigned)u << 16);
}

// ---- init: zero deg ----
__global__ __launch_bounds__(256) void init_kernel(int* __restrict__ deg) {
    const int gid = blockIdx.x * blockDim.x + threadIdx.x;
    if (gid < N_NODES) deg[gid] = 0;
}

// ---- CSR build: histogram ----
__global__ __launch_bounds__(256) void hist_kernel(const int* __restrict__ etgt,
                                                   int* __restrict__ deg) {
    const int stride = gridDim.x * blockDim.x;
    for (int i = blockIdx.x * blockDim.x + threadIdx.x; i < TE; i += stride)
        atomicAdd(&deg[etgt[i]], 1);
}

// ---- hierarchical scan, stage 1: per-block sums (coalesced) ----
__global__ __launch_bounds__(256) void scan1_kernel(const int* __restrict__ deg,
                                                    int* __restrict__ bsum) {
    __shared__ int ws[4];
    const int t = threadIdx.x;
    const int gid = blockIdx.x * 256 + t;
    int d = (gid < N_NODES) ? deg[gid] : 0;
    d += __shfl_xor(d, 1);
    d += __shfl_xor(d, 2);
    d += __shfl_xor(d, 4);
    d += __shfl_xor(d, 8);
    d += __shfl_xor(d, 16);
    d += __shfl_xor(d, 32);
    if ((t & 63) == 0) ws[t >> 6] = d;
    __syncthreads();
    if (t == 0) bsum[blockIdx.x] = ws[0] + ws[1] + ws[2] + ws[3];
}

// ---- hierarchical scan, stage 2: exclusive scan of 118 block sums (1 block) ----
__global__ __launch_bounds__(128) void scan2_kernel(const int* __restrict__ bsum,
                                                    int* __restrict__ boff) {
    __shared__ int s[128];
    const int t = threadIdx.x;
    s[t] = (t < NBLK) ? bsum[t] : 0;
    __syncthreads();
    for (int d = 1; d < 128; d <<= 1) {
        const int v = (t >= d) ? s[t - d] : 0;
        __syncthreads();
        s[t] += v;
        __syncthreads();
    }
    if (t < NBLK) boff[t] = (t > 0) ? s[t - 1] : 0;
}

// ---- hierarchical scan, stage 3: in-block exclusive scan + block base (coalesced) ----
__global__ __launch_bounds__(256) void scan3_kernel(const int* __restrict__ deg,
                                                    const int* __restrict__ boff,
                                                    int* __restrict__ off,
                                                    int* __restrict__ cursor) {
    __shared__ int s[256];
    const int t = threadIdx.x;
    const int gid = blockIdx.x * 256 + t;
    const int d = (gid < N_NODES) ? deg[gid] : 0;
    s[t] = d;
    __syncthreads();
    for (int dd = 1; dd < 256; dd <<= 1) {
        const int v = (t >= dd) ? s[t - dd] : 0;
        __syncthreads();
        s[t] += v;
        __syncthreads();
    }
    if (gid < N_NODES) {
        const int excl = s[t] - d + boff[blockIdx.x];
        off[gid] = excl;
        cursor[gid] = excl;
    }
}

// ---- CSR build: scatter PACKED (src | t<<16) into per-target buckets ----
__global__ __launch_bounds__(256) void scatter_kernel(const int* __restrict__ etgt,
                                                      const int* __restrict__ esrc,
                                                      int* __restrict__ cursor,
                                                      int* __restrict__ perm) {
    const int stride = gridDim.x * blockDim.x;
    for (int e = blockIdx.x * blockDim.x + threadIdx.x; e < TE; e += stride) {
        const int pos = atomicAdd(&cursor[etgt[e]], 1);
        perm[pos] = esrc[e] | ((e / EPT) << 16);
    }
}

// ---- merged prep: [0,1792) weight_prep | [1792,9292) h2bf | [9292,9372) vrelT | [9372,9628) owb ----
__global__ __launch_bounds__(256) void prep_all(const float* __restrict__ kqv_w,
                                                const float* __restrict__ kqv_b,
                                                const float* __restrict__ k_rel,
                                                const float* __restrict__ p_rel,
                                                const float* __restrict__ h,
                                                const float* __restrict__ v_rel,
                                                const float* __restrict__ out_w,
                                                unsigned short* __restrict__ Wcat,
                                                float* __restrict__ bias_cat,
                                                unsigned short* __restrict__ hb,
                                                unsigned short* __restrict__ vrelT,
                                                unsigned short* __restrict__ Wob) {
    const int bid = blockIdx.x;
    const int tid = threadIdx.x;
    if (bid < 1792) {
        const int r = bid, f = tid;
        if (r < 1280) {
            const int t = r >> 8, hh = (r >> 6) & 3, d = r & 63;
            const float sc = 0.125f * p_rel[t * NHEAD + hh];
            float acc = 0.f;
#pragma unroll
            for (int fp = 0; fp < 64; ++fp)
                acc = fmaf(kqv_w[(size_t)(hh * 64 + fp) * 256 + f], k_rel[t * 4096 + fp * 64 + d], acc);
            Wcat[(size_t)r * 256 + f] = f2bf(acc * sc);
            if (f == 0) {
                float b = 0.f;
#pragma unroll
                for (int fp = 0; fp < 64; ++fp)
                    b = fmaf(kqv_b[hh * 64 + fp], k_rel[t * 4096 + fp * 64 + d], b);
                bias_cat[r] = b * sc;
            }
        } else {
            const int src_row = r - 1024;  // 1280->256 (Q), 1536->512 (V)
            Wcat[(size_t)r * 256 + f] = f2bf(kqv_w[(size_t)src_row * 256 + f]);
            if (f == 0) bias_cat[r] = kqv_b[src_row];
        }
    } else if (bid < 9292) {
        const int i = (bid - 1792) * 256 + tid;   // exactly 1,920,000 float4s
        const float4 v = ((const float4*)h)[i];
        ushort4 u;
        u.x = f2bf(v.x); u.y = f2bf(v.y); u.z = f2bf(v.z); u.w = f2bf(v.w);
        ((ushort4*)hb)[i] = u;
    } else if (bid < 9372) {
        const int idx = (bid - 9292) * 256 + tid;
        if (idx < 64 * 320) {
            const int f = idx / 320, k = idx - f * 320;
            vrelT[f * 320 + k] = f2bf(v_rel[(k >> 6) * 4096 + (k & 63) * 64 + f]);
        }
    } else {
        const int i = (bid - 9372) * 256 + tid;   // exactly 65,536
        Wob[i] = f2bf(out_w[i]);
    }
}

// ---- MFMA GEMM v2: Ccat[30000,1792](bf16) = hb[30000,256] @ Wcat^T + bias_cat ----
// BARRIER-FREE K-loop (round-16 tail_fused lesson): with the XCD-chunked swizzle each
// XCD's working set (hb panel ~1.9MB + Wcat 0.9MB) is L2-resident, so A/B fragments are
// read DIRECTLY from global in MFMA layout — no LDS staging, no vmcnt(0) barrier drains.
// 2x inter-wave read redundancy absorbed by L1/L2. Epilogue keeps the proven
// LDS-transpose (own 8.4KB buffer). Numerics: bit-identical to v1.
__global__ __launch_bounds__(256) void mfma_gemm(const unsigned short* __restrict__ hb,
                                                 const unsigned short* __restrict__ Wcat,
                                                 const float* __restrict__ bias_cat,
                                                 unsigned short* __restrict__ Ccat) {
    __shared__ unsigned short Ts[32 * 132];      // epilogue transpose tile only (8.4KB)
    // bijective chunked swizzle over 3290 = 235*14 blocks, 8 XCDs (m204)
    const int orig = blockIdx.x;
    const int xcd = orig & 7, pos = orig >> 3;
    const int q = 3290 / 8, r = 3290 % 8;  // 411, 2
    const int wgid = (xcd < r ? xcd * (q + 1) : r * (q + 1) + (xcd - r) * q) + pos;
    const int brow0 = (wgid / 14) * 128;
    const int bcol0 = (wgid % 14) * 128;

    const int t = threadIdx.x;
    const int wid = t >> 6, lane = t & 63;
    const int wr = wid >> 1, wc = wid & 1;
    const int lrow = lane & 15, kb = lane >> 4;

    // per-lane fragment row addresses (A clamped; B always < 1792)
    size_t arow[4];
#pragma unroll
    for (int m = 0; m < 4; ++m)
        arow[m] = (size_t)min(brow0 + wr * 64 + m * 16 + lrow, N_NODES - 1);
    size_t brow_[4];
#pragma unroll
    for (int n = 0; n < 4; ++n)
        brow_[n] = (size_t)(bcol0 + wc * 64 + n * 16 + lrow);

    f32x4 acc[4][4];
#pragma unroll
    for (int m = 0; m < 4; ++m)
#pragma unroll
        for (int n = 0; n < 4; ++n) acc[m][n] = (f32x4)0.f;

    for (int kt = 0; kt < KDIM; kt += 32) {
        short8 af[4], bfr[4];
#pragma unroll
        for (int m = 0; m < 4; ++m)
            af[m] = *(const short8*)(hb + arow[m] * KDIM + kt + kb * 8);
#pragma unroll
        for (int n = 0; n < 4; ++n)
            bfr[n] = *(const short8*)(Wcat + brow_[n] * KDIM + kt + kb * 8);
#pragma unroll
        for (int m = 0; m < 4; ++m)
#pragma unroll
            for (int n = 0; n < 4; ++n)
                acc[m][n] = __builtin_amdgcn_mfma_f32_16x16x32_bf16(af[m], bfr[n], acc[m][n], 0, 0, 0);
    }

    // ---- LDS-transpose epilogue: dwordx4 C-stores (proven; own Ts buffer) ----
    float bias4[4];
#pragma unroll
    for (int n = 0; n < 4; ++n) bias4[n] = bias_cat[bcol0 + wc * 64 + n * 16 + lrow];
    const int lrw = wr * 16 + kb * 4;
    const int lcw = wc * 64 + lrow;
#pragma unroll
    for (int m = 0; m < 4; ++m) {
        __syncthreads();   // prev m's reads done before overwriting Ts
#pragma unroll
        for (int n = 0; n < 4; ++n)
#pragma unroll
            for (int v = 0; v < 4; ++v)
                Ts[(lrw + v) * 132 + lcw + n * 16] = f2bf(acc[m][n][v] + bias4[n]);
        __syncthreads();
#pragma unroll
        for (int rd = 0; rd < 2; ++rd) {
            const int lr = (t >> 4) + rd * 16;          // 0..31
            const int c0 = (t & 15) * 8;                // 0..120 step 8
            const int grow = brow0 + (lr >> 4) * 64 + m * 16 + (lr & 15);
            if (grow < N_NODES) {
                const uint2 lo = *(const uint2*)&Ts[lr * 132 + c0];
                const uint2 hi = *(const uint2*)&Ts[lr * 132 + c0 + 4];
                const uint4 o = make_uint4(lo.x, lo.y, hi.x, hi.y);
                *(uint4*)&Ccat[(size_t)grow * NCAT + bcol0 + c0] = o;
            }
        }
    }
}

// ---- fused edge pass: one wave per target, packed-src CSR walk (round-10 text). ----
__global__ __launch_bounds__(256) void edge_fused(const unsigned short* __restrict__ Ccat,
                                                  const int* __restrict__ off,
                                                  const int* __restrict__ perm,
                                                  unsigned short* __restrict__ Acat) {
    const int wid = threadIdx.x >> 6, lane = threadIdx.x & 63;
    const int tgt = (blockIdx.x << 2) + wid;
    const int h = lane >> 4, f0 = (lane & 15) << 2;
    const int off0 = off[tgt];
    const int off1 = (tgt == N_NODES - 1) ? TE : off[tgt + 1];
    const ushort4 qu = *(const ushort4*)(Ccat + (size_t)tgt * NCAT + 1280 + (h << 6) + f0);
    const float qx = bf2f(qu.x), qy = bf2f(qu.y), qz = bf2f(qu.z), qw = bf2f(qu.w);
    const int voff = 1536 + (h << 6) + f0;
    float es = 0.f;
    float4 a0 = make_float4(0, 0, 0, 0), a1 = a0, a2 = a0, a3 = a0, a4 = a0;
    int i = off0;
    while (i < off1) {
        const bool two = (i + 1 < off1);
        const int pk0 = perm[i];
        const int pk1 = two ? perm[i + 1] : pk0;
        const int s0 = pk0 & 0xFFFF, t0 = pk0 >> 16;
        const int s1 = pk1 & 0xFFFF, t1 = pk1 >> 16;
        const size_t rb0 = (size_t)s0 * NCAT, rb1 = (size_t)s1 * NCAT;
        // issue all 4 gathers before any compute (2x memory-level parallelism)
        const ushort4 ku0 = *(const ushort4*)(Ccat + rb0 + ((t0 * 4 + h) << 6) + f0);
        const ushort4 vu0 = *(const ushort4*)(Ccat + rb0 + voff);
        const ushort4 ku1 = *(const ushort4*)(Ccat + rb1 + ((t1 * 4 + h) << 6) + f0);
        const ushort4 vu1 = *(const ushort4*)(Ccat + rb1 + voff);
        float p0 = qx * bf2f(ku0.x) + qy * bf2f(ku0.y) + qz * bf2f(ku0.z) + qw * bf2f(ku0.w);
        float p1 = qx * bf2f(ku1.x) + qy * bf2f(ku1.y) + qz * bf2f(ku1.z) + qw * bf2f(ku1.w);
        p0 += __shfl_xor(p0, 1); p1 += __shfl_xor(p1, 1);
        p0 += __shfl_xor(p0, 2); p1 += __shfl_xor(p1, 2);
        p0 += __shfl_xor(p0, 4); p1 += __shfl_xor(p1, 4);
        p0 += __shfl_xor(p0, 8); p1 += __shfl_xor(p1, 8);
        {
            const float ex = __expf(p0);
            es += ex;
            const float mx = ex * bf2f(vu0.x), my = ex * bf2f(vu0.y);
            const float mz = ex * bf2f(vu0.z), mw = ex * bf2f(vu0.w);
            if (t0 == 0)      { a0.x += mx; a0.y += my; a0.z += mz; a0.w += mw; }
            else if (t0 == 1) { a1.x += mx; a1.y += my; a1.z += mz; a1.w += mw; }
            else if (t0 == 2) { a2.x += mx; a2.y += my; a2.z += mz; a2.w += mw; }
            else if (t0 == 3) { a3.x += mx; a3.y += my; a3.z += mz; a3.w += mw; }
            else              { a4.x += mx; a4.y += my; a4.z += mz; a4.w += mw; }
        }
        if (two) {
            const float ex = __expf(p1);
            es += ex;
            const float mx = ex * bf2f(vu1.x), my = ex * bf2f(vu1.y);
            const float mz = ex * bf2f(vu1.z), mw = ex * bf2f(vu1.w);
            if (t1 == 0)      { a0.x += mx; a0.y += my; a0.z += mz; a0.w += mw; }
            else if (t1 == 1) { a1.x += mx; a1.y += my; a1.z += mz; a1.w += mw; }
            else if (t1 == 2) { a2.x += mx; a2.y += my; a2.z += mz; a2.w += mw; }
            else if (t1 == 3) { a3.x += mx; a3.y += my; a3.z += mz; a3.w += mw; }
            else              { a4.x += mx; a4.y += my; a4.z += mz; a4.w += mw; }
        }
        i += two ? 2 : 1;
    }
    const float inv = 1.f / (es + 1e-16f);
    const size_t rr = (size_t)tgt * NHEAD + h;
    unsigned short* base = Acat + rr * (NTYPES * HDIM) + f0;
    ushort4 u;
    u.x = f2bf(a0.x * inv); u.y = f2bf(a0.y * inv); u.z = f2bf(a0.z * inv); u.w = f2bf(a0.w * inv);
    *(ushort4*)(base + 0 * HDIM) = u;
    u.x = f2bf(a1.x * inv); u.y = f2bf(a1.y * inv); u.z = f2bf(a1.z * inv); u.w = f2bf(a1.w * inv);
    *(ushort4*)(base + 1 * HDIM) = u;
    u.x = f2bf(a2.x * inv); u.y = f2bf(a2.y * inv); u.z = f2bf(a2.z * inv); u.w = f2bf(a2.w * inv);
    *(ushort4*)(base + 2 * HDIM) = u;
    u.x = f2bf(a3.x * inv); u.y = f2bf(a3.y * inv); u.z = f2bf(a3.z * inv); u.w = f2bf(a3.w * inv);
    *(ushort4*)(base + 3 * HDIM) = u;
    u.x = f2bf(a4.x * inv); u.y = f2bf(a4.y * inv); u.z = f2bf(a4.z * inv); u.w = f2bf(a4.w * inv);
    *(ushort4*)(base + 4 * HDIM) = u;
}

// ---- FUSED TAIL v3: 64 nodes/block, 256 threads (4 waves), grid 469. BARRIER-FREE loops. ----
__global__ __launch_bounds__(256) void tail_fused(const unsigned short* __restrict__ Acat,
                                                  const unsigned short* __restrict__ vrelT,
                                                  const unsigned short* __restrict__ Wob,
                                                  const float* __restrict__ bias,
                                                  float* __restrict__ C,
                                                  const unsigned short* __restrict__ hres,
                                                  const float* __restrict__ skip) {
    __shared__ unsigned short Gs[64 * 264];      // gelu intermediate, stride 264 (2-way banks, free)
    const int t = threadIdx.x;
    const int wid = t >> 6, lane = t & 63;
    const int lrow = lane & 15, kb = lane >> 4;
    const int n0 = blockIdx.x * 64;              // first node of block
    const size_t ar0 = (size_t)n0 * 4;           // first Acat row (256 rows per block)

    // ================= phase 1: G = gelu(Acat @ vrelT^T) -> Gs (no barriers in loop) ====
    {
        f32x4 acc[4][4];
#pragma unroll
        for (int m = 0; m < 4; ++m)
#pragma unroll
            for (int n = 0; n < 4; ++n) acc[m][n] = (f32x4)0.f;

        size_t arow[4];
#pragma unroll
        for (int m = 0; m < 4; ++m)
            arow[m] = min(ar0 + (size_t)(wid * 64 + m * 16 + lrow), (size_t)120000 - 1);

        for (int kt = 0; kt < 320; kt += 32) {
            short8 af[4], bf_[4];
#pragma unroll
            for (int m = 0; m < 4; ++m)
                af[m] = *(const short8*)(Acat + arow[m] * 320 + kt + kb * 8);
#pragma unroll
            for (int n = 0; n < 4; ++n)
                bf_[n] = *(const short8*)(vrelT + (size_t)(n * 16 + lrow) * 320 + kt + kb * 8);
#pragma unroll
            for (int m = 0; m < 4; ++m)
#pragma unroll
                for (int n = 0; n < 4; ++n)
                    acc[m][n] = __builtin_amdgcn_mfma_f32_16x16x32_bf16(af[m], bf_[n], acc[m][n], 0, 0, 0);
        }
#pragma unroll
        for (int m = 0; m < 4; ++m)
#pragma unroll
            for (int v = 0; v < 4; ++v) {
                const int lr = wid * 64 + m * 16 + kb * 4 + v;   // local Acat row 0..255
#pragma unroll
                for (int n = 0; n < 4; ++n) {
                    const int col = n * 16 + lrow;
                    const float x = acc[m][n][v];
                    const float g = 0.5f * x * (1.f + erff(x * 0.7071067811865475f));
                    Gs[(lr >> 2) * 264 + (lr & 3) * 64 + col] = f2bf(g);
                }
            }
    }
    __syncthreads();   // Gs complete — the ONLY barrier

    // ================= phase 2: out[64,256] = sa*(G @ Wob^T + b) + sb*hb (no barriers) ====
    {
        const int wc = wid;                      // each wave owns one 64-col tile
        f32x4 acc[4][4];
#pragma unroll
        for (int m = 0; m < 4; ++m)
#pragma unroll
            for (int n = 0; n < 4; ++n) acc[m][n] = (f32x4)0.f;

        for (int kt = 0; kt < 256; kt += 32) {
            short8 af[4], bfr[4];
#pragma unroll
            for (int m = 0; m < 4; ++m)
                af[m] = *(const short8*)&Gs[(m * 16 + lrow) * 264 + kt + kb * 8];
#pragma unroll
            for (int n = 0; n < 4; ++n)
                bfr[n] = *(const short8*)(Wob + (size_t)(wc * 64 + n * 16 + lrow) * 256 + kt + kb * 8);
#pragma unroll
            for (int m = 0; m < 4; ++m)
#pragma unroll
                for (int n = 0; n < 4; ++n)
                    acc[m][n] = __builtin_amdgcn_mfma_f32_16x16x32_bf16(af[m], bfr[n], acc[m][n], 0, 0, 0);
        }

        const float s = skip[0];
        const float sa = 1.f / (1.f + expf(-s));
        const float sb = 1.f - sa;
        float bias4[4];
#pragma unroll
        for (int n = 0; n < 4; ++n) bias4[n] = bias[wc * 64 + n * 16 + lrow];
#pragma unroll
        for (int m = 0; m < 4; ++m) {
            const int gr0 = n0 + m * 16 + kb * 4;
#pragma unroll
            for (int v = 0; v < 4; ++v) {
                const int grow = gr0 + v;
                if (grow < N_NODES) {
#pragma unroll
                    for (int n = 0; n < 4; ++n) {
                        const int gcol = wc * 64 + n * 16 + lrow;
                        const float val = acc[m][n][v] + bias4[n];
                        C[(size_t)grow * 256 + gcol] = sa * val + sb * bf2f(hres[(size_t)grow * 256 + gcol]);
                    }
                }
            }
        }
    }
}

extern "C" void kernel_launch(void* const* d_in, const int* in_sizes, int n_in,
                              void* d_out, int out_size, void* d_ws, size_t ws_size,
                              hipStream_t stream) {
    const float* h      = (const float*)d_in[0];
    const int*   esrc   = (const int*)d_in[1];
    const int*   etgt   = (const int*)d_in[2];
    const float* kqv_w  = (const float*)d_in[3];
    const float* kqv_b  = (const float*)d_in[4];
    const float* out_w  = (const float*)d_in[5];
    const float* out_b  = (const float*)d_in[6];
    const float* k_rel  = (const float*)d_in[7];
    const float* v_rel  = (const float*)d_in[8];
    const float* skip   = (const float*)d_in[9];
    const float* p_rel  = (const float*)d_in[10];
    float* out = (float*)d_out;

    // workspace layout (float-sized slots):
    float* ws = (float*)d_ws;
    unsigned short* Ccat     = (unsigned short*)ws;                 // 26,880,000 slots [0 .. 26.88M)
    int*            deg      = (int*)(ws + 26880000);               //     30,000 -> 26,910,000
    int*            off      = (int*)(ws + 26910000);               //     30,000 -> 26,940,000
    int*            cursor   = (int*)(ws + 26940000);               //     30,000 -> 26,970,000
    int*            perm     = (int*)(ws + 26970000);               //    200,000 -> 27,170,000
    unsigned short* Acat     = (unsigned short*)(ws + 31010000);    // 19,200,000 slots -> 50,210,000
    // LATE-READ buffers (consumed AFTER Acat is written) -> past Acat's end:
    unsigned short* vrelT    = (unsigned short*)(ws + 50210000);    // 10,240 slots -> 50,220,240
    unsigned short* Wob      = (unsigned short*)(ws + 50220240);    // 32,768 slots -> 50,253,008
    unsigned short* hb       = (unsigned short*)(ws + 50253008);    // 3,840,000 slots -> 54,093,008
    int*            bsum     = (int*)(ws + 54093008);               //        118 -> 54,093,126
    int*            boff     = (int*)(ws + 54093126);               //        118 -> 54,093,244
    // EARLY-DEAD aliases inside Acat's span (read only BEFORE edge_fused writes Acat):
    unsigned short* Wcat     = (unsigned short*)(ws + 45370000);    // 229,376 slots -> ends 45,599,376
    float*          bias_cat = ws + 45600000;                       // 1,792 -> ends 45,601,792 (< 50.21M ok)
    // total footprint: 54,093,244 float slots = 216.4 MB (round 3 proved >= 219.9 MB available)

    hipLaunchKernelGGL(init_kernel, dim3(NBLK), dim3(256), 0, stream, deg);
    hipLaunchKernelGGL(hist_kernel, dim3(782), dim3(256), 0, stream, etgt, deg);
    hipLaunchKernelGGL(scan1_kernel, dim3(NBLK), dim3(256), 0, stream, deg, bsum);
    hipLaunchKernelGGL(scan2_kernel, dim3(1), dim3(128), 0, stream, bsum, boff);
    hipLaunchKernelGGL(scan3_kernel, dim3(NBLK), dim3(256), 0, stream, deg, boff, off, cursor);
    hipLaunchKernelGGL(scatter_kernel, dim3(782), dim3(256), 0, stream, etgt, esrc, cursor, perm);
    hipLaunchKernelGGL(prep_all, dim3(9628), dim3(256), 0, stream,
                       kqv_w, kqv_b, k_rel, p_rel, h, v_rel, out_w,
                       Wcat, bias_cat, hb, vrelT, Wob);
    hipLaunchKernelGGL(mfma_gemm, dim3(3290), dim3(256), 0, stream,
                       hb, Wcat, bias_cat, Ccat);
    hipLaunchKernelGGL(edge_fused, dim3(N_NODES / 4), dim3(256), 0, stream,
                       Ccat, off, perm, Acat);
    hipLaunchKernelGGL(tail_fused, dim3(469), dim3(256), 0, stream,
                       Acat, vrelT, Wob, out_b, out, hb, skip);
}

// Round 18
// 179.279 us; speedup vs baseline: 1.3038x; 1.3038x over previous
//
#include <hip/hip_runtime.h>
#include <hip/hip_bf16.h>
#include <math.h>

#define N_NODES 30000
#define NHEAD   4
#define HDIM    64
#define NTYPES  5
#define EPT     40000
#define TE      (NTYPES * EPT)
#define KDIM    256
#define NCAT    1792   // 1280 Ktil | 256 Q | 256 V
#define NBLK    118    // ceil(30000/256)

typedef __attribute__((ext_vector_type(8))) short short8;
typedef __attribute__((ext_vector_type(4))) float f32x4;

__device__ __forceinline__ unsigned short f2bf(float f) {
    __hip_bfloat16 h = __float2bfloat16(f);
    return *reinterpret_cast<unsigned short*>(&h);
}
__device__ __forceinline__ float bf2f(unsigned short u) {
    return __uint_as_float((unsigned)u << 16);
}

// async global->LDS, 16B per lane. LDS dest is wave-uniform base + lane*16 (linear).
__device__ __forceinline__ void gload16(const unsigned short* g, unsigned short* l) {
    __builtin_amdgcn_global_load_lds((const __attribute__((address_space(1))) void*)g,
                                     (__attribute__((address_space(3))) void*)l, 16, 0, 0);
}

// ---- init: zero deg ----
__global__ __launch_bounds__(256) void init_kernel(int* __restrict__ deg) {
    const int gid = blockIdx.x * blockDim.x + threadIdx.x;
    if (gid < N_NODES) deg[gid] = 0;
}

// ---- CSR build: histogram ----
__global__ __launch_bounds__(256) void hist_kernel(const int* __restrict__ etgt,
                                                   int* __restrict__ deg) {
    const int stride = gridDim.x * blockDim.x;
    for (int i = blockIdx.x * blockDim.x + threadIdx.x; i < TE; i += stride)
        atomicAdd(&deg[etgt[i]], 1);
}

// ---- hierarchical scan, stage 1: per-block sums (coalesced) ----
__global__ __launch_bounds__(256) void scan1_kernel(const int* __restrict__ deg,
                                                    int* __restrict__ bsum) {
    __shared__ int ws[4];
    const int t = threadIdx.x;
    const int gid = blockIdx.x * 256 + t;
    int d = (gid < N_NODES) ? deg[gid] : 0;
    d += __shfl_xor(d, 1);
    d += __shfl_xor(d, 2);
    d += __shfl_xor(d, 4);
    d += __shfl_xor(d, 8);
    d += __shfl_xor(d, 16);
    d += __shfl_xor(d, 32);
    if ((t & 63) == 0) ws[t >> 6] = d;
    __syncthreads();
    if (t == 0) bsum[blockIdx.x] = ws[0] + ws[1] + ws[2] + ws[3];
}

// ---- hierarchical scan, stage 2: exclusive scan of 118 block sums (1 block) ----
__global__ __launch_bounds__(128) void scan2_kernel(const int* __restrict__ bsum,
                                                    int* __restrict__ boff) {
    __shared__ int s[128];
    const int t = threadIdx.x;
    s[t] = (t < NBLK) ? bsum[t] : 0;
    __syncthreads();
    for (int d = 1; d < 128; d <<= 1) {
        const int v = (t >= d) ? s[t - d] : 0;
        __syncthreads();
        s[t] += v;
        __syncthreads();
    }
    if (t < NBLK) boff[t] = (t > 0) ? s[t - 1] : 0;
}

// ---- hierarchical scan, stage 3: in-block exclusive scan + block base (coalesced) ----
__global__ __launch_bounds__(256) void scan3_kernel(const int* __restrict__ deg,
                                                    const int* __restrict__ boff,
                                                    int* __restrict__ off,
                                                    int* __restrict__ cursor) {
    __shared__ int s[256];
    const int t = threadIdx.x;
    const int gid = blockIdx.x * 256 + t;
    const int d = (gid < N_NODES) ? deg[gid] : 0;
    s[t] = d;
    __syncthreads();
    for (int dd = 1; dd < 256; dd <<= 1) {
        const int v = (t >= dd) ? s[t - dd] : 0;
        __syncthreads();
        s[t] += v;
        __syncthreads();
    }
    if (gid < N_NODES) {
        const int excl = s[t] - d + boff[blockIdx.x];
        off[gid] = excl;
        cursor[gid] = excl;
    }
}

// ---- CSR build: scatter PACKED (src | t<<16) into per-target buckets ----
__global__ __launch_bounds__(256) void scatter_kernel(const int* __restrict__ etgt,
                                                      const int* __restrict__ esrc,
                                                      int* __restrict__ cursor,
                                                      int* __restrict__ perm) {
    const int stride = gridDim.x * blockDim.x;
    for (int e = blockIdx.x * blockDim.x + threadIdx.x; e < TE; e += stride) {
        const int pos = atomicAdd(&cursor[etgt[e]], 1);
        perm[pos] = esrc[e] | ((e / EPT) << 16);
    }
}

// ---- merged prep: [0,1792) weight_prep | [1792,9292) h2bf | [9292,9372) vrelT | [9372,9628) owb ----
__global__ __launch_bounds__(256) void prep_all(const float* __restrict__ kqv_w,
                                                const float* __restrict__ kqv_b,
                                                const float* __restrict__ k_rel,
                                                const float* __restrict__ p_rel,
                                                const float* __restrict__ h,
                                                const float* __restrict__ v_rel,
                                                const float* __restrict__ out_w,
                                                unsigned short* __restrict__ Wcat,
                                                float* __restrict__ bias_cat,
                                                unsigned short* __restrict__ hb,
                                                unsigned short* __restrict__ vrelT,
                                                unsigned short* __restrict__ Wob) {
    const int bid = blockIdx.x;
    const int tid = threadIdx.x;
    if (bid < 1792) {
        const int r = bid, f = tid;
        if (r < 1280) {
            const int t = r >> 8, hh = (r >> 6) & 3, d = r & 63;
            const float sc = 0.125f * p_rel[t * NHEAD + hh];
            float acc = 0.f;
#pragma unroll
            for (int fp = 0; fp < 64; ++fp)
                acc = fmaf(kqv_w[(size_t)(hh * 64 + fp) * 256 + f], k_rel[t * 4096 + fp * 64 + d], acc);
            Wcat[(size_t)r * 256 + f] = f2bf(acc * sc);
            if (f == 0) {
                float b = 0.f;
#pragma unroll
                for (int fp = 0; fp < 64; ++fp)
                    b = fmaf(kqv_b[hh * 64 + fp], k_rel[t * 4096 + fp * 64 + d], b);
                bias_cat[r] = b * sc;
            }
        } else {
            const int src_row = r - 1024;  // 1280->256 (Q), 1536->512 (V)
            Wcat[(size_t)r * 256 + f] = f2bf(kqv_w[(size_t)src_row * 256 + f]);
            if (f == 0) bias_cat[r] = kqv_b[src_row];
        }
    } else if (bid < 9292) {
        const int i = (bid - 1792) * 256 + tid;   // exactly 1,920,000 float4s
        const float4 v = ((const float4*)h)[i];
        ushort4 u;
        u.x = f2bf(v.x); u.y = f2bf(v.y); u.z = f2bf(v.z); u.w = f2bf(v.w);
        ((ushort4*)hb)[i] = u;
    } else if (bid < 9372) {
        const int idx = (bid - 9292) * 256 + tid;
        if (idx < 64 * 320) {
            const int f = idx / 320, k = idx - f * 320;
            vrelT[f * 320 + k] = f2bf(v_rel[(k >> 6) * 4096 + (k & 63) * 64 + f]);
        }
    } else {
        const int i = (bid - 9372) * 256 + tid;   // exactly 65,536
        Wob[i] = f2bf(out_w[i]);
    }
}

// ---- MFMA GEMM (round-16 proven): Ccat = hb @ Wcat^T + bias_cat ----
// 128x128 tile, BK=32, 2-phase gload16 dbuf, XCD-chunked swizzle, LDS-transpose epilogue.
__global__ __launch_bounds__(256) void mfma_gemm(const unsigned short* __restrict__ hb,
                                                 const unsigned short* __restrict__ Wcat,
                                                 const float* __restrict__ bias_cat,
                                                 unsigned short* __restrict__ Ccat) {
    __shared__ unsigned short As[2][128 * 32];
    __shared__ unsigned short Bs[2][128 * 32];
    // bijective chunked swizzle over 3290 = 235*14 blocks, 8 XCDs (m204)
    const int orig = blockIdx.x;
    const int xcd = orig & 7, pos = orig >> 3;
    const int q = 3290 / 8, r = 3290 % 8;  // 411, 2
    const int wgid = (xcd < r ? xcd * (q + 1) : r * (q + 1) + (xcd - r) * q) + pos;
    const int brow0 = (wgid / 14) * 128;
    const int bcol0 = (wgid % 14) * 128;

    const int t = threadIdx.x;
    const int wid = t >> 6, lane = t & 63;
    const int wr = wid >> 1, wc = wid & 1;
    const int lrow = lane & 15, kb = lane >> 4;
    const int srow = lane >> 2;
    const int schunk = ((lane & 3) ^ ((lane >> 3) & 3)) * 8;   // staged (swizzled) chunk
    const int rchunk = (kb ^ ((lrow >> 1) & 3)) * 8;           // swizzled read chunk

    const int arow0 = min(brow0 + wid * 16 + srow, N_NODES - 1);
    const int arow1 = min(brow0 + 64 + wid * 16 + srow, N_NODES - 1);
    const int brw0 = bcol0 + wid * 16 + srow;        // always < 1792
    const int brw1 = bcol0 + 64 + wid * 16 + srow;

    auto stage = [&](int buf, int kt) {
        gload16(hb + (size_t)arow0 * KDIM + kt + schunk, &As[buf][wid * 512]);
        gload16(hb + (size_t)arow1 * KDIM + kt + schunk, &As[buf][2048 + wid * 512]);
        gload16(Wcat + (size_t)brw0 * KDIM + kt + schunk, &Bs[buf][wid * 512]);
        gload16(Wcat + (size_t)brw1 * KDIM + kt + schunk, &Bs[buf][2048 + wid * 512]);
    };

    f32x4 acc[4][4];
#pragma unroll
    for (int m = 0; m < 4; ++m)
#pragma unroll
        for (int n = 0; n < 4; ++n) acc[m][n] = (f32x4)0.f;

    stage(0, 0);
    __syncthreads();
    int cur = 0;
    for (int kt = 0; kt < KDIM; kt += 32) {
        if (kt + 32 < KDIM) stage(cur ^ 1, kt + 32);
        short8 af[4], bfr[4];
#pragma unroll
        for (int m = 0; m < 4; ++m)
            af[m] = *(const short8*)&As[cur][(wr * 64 + m * 16 + lrow) * 32 + rchunk];
#pragma unroll
        for (int n = 0; n < 4; ++n)
            bfr[n] = *(const short8*)&Bs[cur][(wc * 64 + n * 16 + lrow) * 32 + rchunk];
#pragma unroll
        for (int m = 0; m < 4; ++m)
#pragma unroll
            for (int n = 0; n < 4; ++n)
                acc[m][n] = __builtin_amdgcn_mfma_f32_16x16x32_bf16(af[m], bfr[n], acc[m][n], 0, 0, 0);
        __syncthreads();
        cur ^= 1;
    }

    // ---- LDS-transpose epilogue: dwordx4 C-stores ----
    unsigned short* Ts = &As[0][0];
    float bias4[4];
#pragma unroll
    for (int n = 0; n < 4; ++n) bias4[n] = bias_cat[bcol0 + wc * 64 + n * 16 + lrow];
    const int lrw = wr * 16 + kb * 4;
    const int lcw = wc * 64 + lrow;
#pragma unroll
    for (int m = 0; m < 4; ++m) {
        __syncthreads();
#pragma unroll
        for (int n = 0; n < 4; ++n)
#pragma unroll
            for (int v = 0; v < 4; ++v)
                Ts[(lrw + v) * 132 + lcw + n * 16] = f2bf(acc[m][n][v] + bias4[n]);
        __syncthreads();
#pragma unroll
        for (int rd = 0; rd < 2; ++rd) {
            const int lr = (t >> 4) + rd * 16;          // 0..31
            const int c0 = (t & 15) * 8;                // 0..120 step 8
            const int grow = brow0 + (lr >> 4) * 64 + m * 16 + (lr & 15);
            if (grow < N_NODES) {
                const uint2 lo = *(const uint2*)&Ts[lr * 132 + c0];
                const uint2 hi = *(const uint2*)&Ts[lr * 132 + c0 + 4];
                const uint4 o = make_uint4(lo.x, lo.y, hi.x, hi.y);
                *(uint4*)&Ccat[(size_t)grow * NCAT + bcol0 + c0] = o;
            }
        }
    }
}

// ---- fused edge pass: one wave per target, packed-src CSR walk (round-10 text). ----
__global__ __launch_bounds__(256) void edge_fused(const unsigned short* __restrict__ Ccat,
                                                  const int* __restrict__ off,
                                                  const int* __restrict__ perm,
                                                  unsigned short* __restrict__ Acat) {
    const int wid = threadIdx.x >> 6, lane = threadIdx.x & 63;
    const int tgt = (blockIdx.x << 2) + wid;
    const int h = lane >> 4, f0 = (lane & 15) << 2;
    const int off0 = off[tgt];
    const int off1 = (tgt == N_NODES - 1) ? TE : off[tgt + 1];
    const ushort4 qu = *(const ushort4*)(Ccat + (size_t)tgt * NCAT + 1280 + (h << 6) + f0);
    const float qx = bf2f(qu.x), qy = bf2f(qu.y), qz = bf2f(qu.z), qw = bf2f(qu.w);
    const int voff = 1536 + (h << 6) + f0;
    float es = 0.f;
    float4 a0 = make_float4(0, 0, 0, 0), a1 = a0, a2 = a0, a3 = a0, a4 = a0;
    int i = off0;
    while (i < off1) {
        const bool two = (i + 1 < off1);
        const int pk0 = perm[i];
        const int pk1 = two ? perm[i + 1] : pk0;
        const int s0 = pk0 & 0xFFFF, t0 = pk0 >> 16;
        const int s1 = pk1 & 0xFFFF, t1 = pk1 >> 16;
        const size_t rb0 = (size_t)s0 * NCAT, rb1 = (size_t)s1 * NCAT;
        // issue all 4 gathers before any compute (2x memory-level parallelism)
        const ushort4 ku0 = *(const ushort4*)(Ccat + rb0 + ((t0 * 4 + h) << 6) + f0);
        const ushort4 vu0 = *(const ushort4*)(Ccat + rb0 + voff);
        const ushort4 ku1 = *(const ushort4*)(Ccat + rb1 + ((t1 * 4 + h) << 6) + f0);
        const ushort4 vu1 = *(const ushort4*)(Ccat + rb1 + voff);
        float p0 = qx * bf2f(ku0.x) + qy * bf2f(ku0.y) + qz * bf2f(ku0.z) + qw * bf2f(ku0.w);
        float p1 = qx * bf2f(ku1.x) + qy * bf2f(ku1.y) + qz * bf2f(ku1.z) + qw * bf2f(ku1.w);
        p0 += __shfl_xor(p0, 1); p1 += __shfl_xor(p1, 1);
        p0 += __shfl_xor(p0, 2); p1 += __shfl_xor(p1, 2);
        p0 += __shfl_xor(p0, 4); p1 += __shfl_xor(p1, 4);
        p0 += __shfl_xor(p0, 8); p1 += __shfl_xor(p1, 8);
        {
            const float ex = __expf(p0);
            es += ex;
            const float mx = ex * bf2f(vu0.x), my = ex * bf2f(vu0.y);
            const float mz = ex * bf2f(vu0.z), mw = ex * bf2f(vu0.w);
            if (t0 == 0)      { a0.x += mx; a0.y += my; a0.z += mz; a0.w += mw; }
            else if (t0 == 1) { a1.x += mx; a1.y += my; a1.z += mz; a1.w += mw; }
            else if (t0 == 2) { a2.x += mx; a2.y += my; a2.z += mz; a2.w += mw; }
            else if (t0 == 3) { a3.x += mx; a3.y += my; a3.z += mz; a3.w += mw; }
            else              { a4.x += mx; a4.y += my; a4.z += mz; a4.w += mw; }
        }
        if (two) {
            const float ex = __expf(p1);
            es += ex;
            const float mx = ex * bf2f(vu1.x), my = ex * bf2f(vu1.y);
            const float mz = ex * bf2f(vu1.z), mw = ex * bf2f(vu1.w);
            if (t1 == 0)      { a0.x += mx; a0.y += my; a0.z += mz; a0.w += mw; }
            else if (t1 == 1) { a1.x += mx; a1.y += my; a1.z += mz; a1.w += mw; }
            else if (t1 == 2) { a2.x += mx; a2.y += my; a2.z += mz; a2.w += mw; }
            else if (t1 == 3) { a3.x += mx; a3.y += my; a3.z += mz; a3.w += mw; }
            else              { a4.x += mx; a4.y += my; a4.z += mz; a4.w += mw; }
        }
        i += two ? 2 : 1;
    }
    const float inv = 1.f / (es + 1e-16f);
    const size_t rr = (size_t)tgt * NHEAD + h;
    unsigned short* base = Acat + rr * (NTYPES * HDIM) + f0;
    ushort4 u;
    u.x = f2bf(a0.x * inv); u.y = f2bf(a0.y * inv); u.z = f2bf(a0.z * inv); u.w = f2bf(a0.w * inv);
    *(ushort4*)(base + 0 * HDIM) = u;
    u.x = f2bf(a1.x * inv); u.y = f2bf(a1.y * inv); u.z = f2bf(a1.z * inv); u.w = f2bf(a1.w * inv);
    *(ushort4*)(base + 1 * HDIM) = u;
    u.x = f2bf(a2.x * inv); u.y = f2bf(a2.y * inv); u.z = f2bf(a2.z * inv); u.w = f2bf(a2.w * inv);
    *(ushort4*)(base + 2 * HDIM) = u;
    u.x = f2bf(a3.x * inv); u.y = f2bf(a3.y * inv); u.z = f2bf(a3.z * inv); u.w = f2bf(a3.w * inv);
    *(ushort4*)(base + 3 * HDIM) = u;
    u.x = f2bf(a4.x * inv); u.y = f2bf(a4.y * inv); u.z = f2bf(a4.z * inv); u.w = f2bf(a4.w * inv);
    *(ushort4*)(base + 4 * HDIM) = u;
}

// ---- FUSED TAIL v3: 64 nodes/block, 256 threads (4 waves), grid 469. BARRIER-FREE loops. ----
__global__ __launch_bounds__(256) void tail_fused(const unsigned short* __restrict__ Acat,
                                                  const unsigned short* __restrict__ vrelT,
                                                  const unsigned short* __restrict__ Wob,
                                                  const float* __restrict__ bias,
                                                  float* __restrict__ C,
                                                  const unsigned short* __restrict__ hres,
                                                  const float* __restrict__ skip) {
    __shared__ unsigned short Gs[64 * 264];      // gelu intermediate, stride 264 (2-way banks, free)
    const int t = threadIdx.x;
    const int wid = t >> 6, lane = t & 63;
    const int lrow = lane & 15, kb = lane >> 4;
    const int n0 = blockIdx.x * 64;              // first node of block
    const size_t ar0 = (size_t)n0 * 4;           // first Acat row (256 rows per block)

    // ================= phase 1: G = gelu(Acat @ vrelT^T) -> Gs (no barriers in loop) ====
    {
        f32x4 acc[4][4];
#pragma unroll
        for (int m = 0; m < 4; ++m)
#pragma unroll
            for (int n = 0; n < 4; ++n) acc[m][n] = (f32x4)0.f;

        size_t arow[4];
#pragma unroll
        for (int m = 0; m < 4; ++m)
            arow[m] = min(ar0 + (size_t)(wid * 64 + m * 16 + lrow), (size_t)120000 - 1);

        for (int kt = 0; kt < 320; kt += 32) {
            short8 af[4], bf_[4];
#pragma unroll
            for (int m = 0; m < 4; ++m)
                af[m] = *(const short8*)(Acat + arow[m] * 320 + kt + kb * 8);
#pragma unroll
            for (int n = 0; n < 4; ++n)
                bf_[n] = *(const short8*)(vrelT + (size_t)(n * 16 + lrow) * 320 + kt + kb * 8);
#pragma unroll
            for (int m = 0; m < 4; ++m)
#pragma unroll
                for (int n = 0; n < 4; ++n)
                    acc[m][n] = __builtin_amdgcn_mfma_f32_16x16x32_bf16(af[m], bf_[n], acc[m][n], 0, 0, 0);
        }
#pragma unroll
        for (int m = 0; m < 4; ++m)
#pragma unroll
            for (int v = 0; v < 4; ++v) {
                const int lr = wid * 64 + m * 16 + kb * 4 + v;   // local Acat row 0..255
#pragma unroll
                for (int n = 0; n < 4; ++n) {
                    const int col = n * 16 + lrow;
                    const float x = acc[m][n][v];
                    const float g = 0.5f * x * (1.f + erff(x * 0.7071067811865475f));
                    Gs[(lr >> 2) * 264 + (lr & 3) * 64 + col] = f2bf(g);
                }
            }
    }
    __syncthreads();   // Gs complete — the ONLY barrier

    // ================= phase 2: out[64,256] = sa*(G @ Wob^T + b) + sb*hb (no barriers) ====
    {
        const int wc = wid;                      // each wave owns one 64-col tile
        f32x4 acc[4][4];
#pragma unroll
        for (int m = 0; m < 4; ++m)
#pragma unroll
            for (int n = 0; n < 4; ++n) acc[m][n] = (f32x4)0.f;

        for (int kt = 0; kt < 256; kt += 32) {
            short8 af[4], bfr[4];
#pragma unroll
            for (int m = 0; m < 4; ++m)
                af[m] = *(const short8*)&Gs[(m * 16 + lrow) * 264 + kt + kb * 8];
#pragma unroll
            for (int n = 0; n < 4; ++n)
                bfr[n] = *(const short8*)(Wob + (size_t)(wc * 64 + n * 16 + lrow) * 256 + kt + kb * 8);
#pragma unroll
            for (int m = 0; m < 4; ++m)
#pragma unroll
                for (int n = 0; n < 4; ++n)
                    acc[m][n] = __builtin_amdgcn_mfma_f32_16x16x32_bf16(af[m], bfr[n], acc[m][n], 0, 0, 0);
        }

        const float s = skip[0];
        const float sa = 1.f / (1.f + expf(-s));
        const float sb = 1.f - sa;
        float bias4[4];
#pragma unroll
        for (int n = 0; n < 4; ++n) bias4[n] = bias[wc * 64 + n * 16 + lrow];
#pragma unroll
        for (int m = 0; m < 4; ++m) {
            const int gr0 = n0 + m * 16 + kb * 4;
#pragma unroll
            for (int v = 0; v < 4; ++v) {
                const int grow = gr0 + v;
                if (grow < N_NODES) {
#pragma unroll
                    for (int n = 0; n < 4; ++n) {
                        const int gcol = wc * 64 + n * 16 + lrow;
                        const float val = acc[m][n][v] + bias4[n];
                        C[(size_t)grow * 256 + gcol] = sa * val + sb * bf2f(hres[(size_t)grow * 256 + gcol]);
                    }
                }
            }
        }
    }
}

extern "C" void kernel_launch(void* const* d_in, const int* in_sizes, int n_in,
                              void* d_out, int out_size, void* d_ws, size_t ws_size,
                              hipStream_t stream) {
    const float* h      = (const float*)d_in[0];
    const int*   esrc   = (const int*)d_in[1];
    const int*   etgt   = (const int*)d_in[2];
    const float* kqv_w  = (const float*)d_in[3];
    const float* kqv_b  = (const float*)d_in[4];
    const float* out_w  = (const float*)d_in[5];
    const float* out_b  = (const float*)d_in[6];
    const float* k_rel  = (const float*)d_in[7];
    const float* v_rel  = (const float*)d_in[8];
    const float* skip   = (const float*)d_in[9];
    const float* p_rel  = (const float*)d_in[10];
    float* out = (float*)d_out;

    // workspace layout (float-sized slots):
    float* ws = (float*)d_ws;
    unsigned short* Ccat     = (unsigned short*)ws;                 // 26,880,000 slots [0 .. 26.88M)
    int*            deg      = (int*)(ws + 26880000);               //     30,000 -> 26,910,000
    int*            off      = (int*)(ws + 26910000);               //     30,000 -> 26,940,000
    int*            cursor   = (int*)(ws + 26940000);               //     30,000 -> 26,970,000
    int*            perm     = (int*)(ws + 26970000);               //    200,000 -> 27,170,000
    unsigned short* Acat     = (unsigned short*)(ws + 31010000);    // 19,200,000 slots -> 50,210,000
    // LATE-READ buffers (consumed AFTER Acat is written) -> past Acat's end:
    unsigned short* vrelT    = (unsigned short*)(ws + 50210000);    // 10,240 slots -> 50,220,240
    unsigned short* Wob      = (unsigned short*)(ws + 50220240);    // 32,768 slots -> 50,253,008
    unsigned short* hb       = (unsigned short*)(ws + 50253008);    // 3,840,000 slots -> 54,093,008
    int*            bsum     = (int*)(ws + 54093008);               //        118 -> 54,093,126
    int*            boff     = (int*)(ws + 54093126);               //        118 -> 54,093,244
    // EARLY-DEAD aliases inside Acat's span (read only BEFORE edge_fused writes Acat):
    unsigned short* Wcat     = (unsigned short*)(ws + 45370000);    // 229,376 slots -> ends 45,599,376
    float*          bias_cat = ws + 45600000;                       // 1,792 -> ends 45,601,792 (< 50.21M ok)
    // total footprint: 54,093,244 float slots = 216.4 MB (round 3 proved >= 219.9 MB available)

    hipLaunchKernelGGL(init_kernel, dim3(NBLK), dim3(256), 0, stream, deg);
    hipLaunchKernelGGL(hist_kernel, dim3(782), dim3(256), 0, stream, etgt, deg);
    hipLaunchKernelGGL(scan1_kernel, dim3(NBLK), dim3(256), 0, stream, deg, bsum);
    hipLaunchKernelGGL(scan2_kernel, dim3(1), dim3(128), 0, stream, bsum, boff);
    hipLaunchKernelGGL(scan3_kernel, dim3(NBLK), dim3(256), 0, stream, deg, boff, off, cursor);
    hipLaunchKernelGGL(scatter_kernel, dim3(782), dim3(256), 0, stream, etgt, esrc, cursor, perm);
    hipLaunchKernelGGL(prep_all, dim3(9628), dim3(256), 0, stream,
                       kqv_w, kqv_b, k_rel, p_rel, h, v_rel, out_w,
                       Wcat, bias_cat, hb, vrelT, Wob);
    hipLaunchKernelGGL(mfma_gemm, dim3(3290), dim3(256), 0, stream,
                       hb, Wcat, bias_cat, Ccat);
    hipLaunchKernelGGL(edge_fused, dim3(N_NODES / 4), dim3(256), 0, stream,
                       Ccat, off, perm, Acat);
    hipLaunchKernelGGL(tail_fused, dim3(469), dim3(256), 0, stream,
                       Acat, vrelT, Wob, out_b, out, hb, skip);
}